// Round 11
// baseline (152.676 us; speedup 1.0000x reference)
//
#include <hip/hip_runtime.h>
#include <math.h>

// Fused SIFT-like pipeline:
//   Sobel(3x3, pad1) -> project onto 8 orientations -> argmax -> magnitude
//   into winning bin -> depthwise 4x4 ones conv (pad2) => out (8,8,1025,1025)
//
// v11 = v6 (proven 88.5us: LDS staging, 1 hist col/lane, pair-sum ring,
// batch==XCD swizzle, DPP horizontal sums, launch_bounds(256,4)) with ONE
// change: nontemporal plane stores (write-once output; bypass L2
// allocate->evict double movement). v10's (256,5) bound caused a VGPR-28
// spill catastrophe - bound stays at 4.
//
// Block = 256 threads (4 waves), tile 61 out cols x 64 out rows; wave owns
// 16 rows. Lane l owns hist col j0-2+l; out col c = hist cols c..c+3 via
// v += shl1(v); v += shl1(shl1(v))  (wave_shl:1 DPP, zero-fill at lane 63;
// lanes 61..63 feed only and never store).

#define TWC 61              // out cols per tile
#define WTH 16              // out rows per wave
#define WPB 4               // waves per block
#define BTH (WPB*WTH)       // 64 out rows per block
#define XC 66               // staged x cols (j0-3 .. j0+62)
#define XR (BTH+5)          // 69 staged x rows
#define PLANE 1050625       // 1025*1025
#define NCT 17              // col tiles
#define NRT 17              // row tiles

// DPP wave_shl:1 (0x130): lane i <- lane i+1, zero-fill (== shfl_down 1;
// direction empirically proven by v6/v7/v8 passing)
__device__ __forceinline__ float wshl1(float v) {
    return __int_as_float(
        __builtin_amdgcn_update_dpp(0, __float_as_int(v), 0x130, 0xf, 0xf, true));
}

__global__ __launch_bounds__(256, 4)
void sift_fused(const float* __restrict__ x,
                const float* __restrict__ ow,
                float* __restrict__ out)
{
    __shared__ float sx[XR * XC];

    const int tid  = threadIdx.x;
    const int lane = tid & 63;
    const int wv   = tid >> 6;

    // XCD-aware remap: batch == XCD (8 batches, 8 XCDs, bijective)
    const int flat = blockIdx.x + NCT * (blockIdx.y + NRT * blockIdx.z);
    const int bb = flat & 7;
    const int t  = flat >> 3;
    const int bx = t % NCT;
    const int by = t / NCT;
    const int j0 = bx * TWC;
    const int r0 = by * BTH;

    // ---- stage x tile into LDS (zero-padded at image borders) ----
    const float* xb = x + (size_t)bb * 1024 * 1024;
    for (int p = tid; p < XR * XC; p += 256) {
        int r = p / XC, c = p - r * XC;
        int gr = r0 - 3 + r, gc = j0 - 3 + c;
        float v = 0.0f;
        if ((unsigned)gr < 1024u && (unsigned)gc < 1024u)
            v = xb[(size_t)gr * 1024 + gc];
        sx[p] = v;
    }
    __syncthreads();

    const int rbase = r0 + WTH * wv;           // first output row of this wave
    if (rbase > 1024) return;                  // no barriers after this point

    // orientation weights (uniform loads)
    float wcn[8], wsn[8];
    #pragma unroll
    for (int o = 0; o < 8; ++o) { wcn[o] = ow[2*o]; wsn[o] = ow[2*o+1]; }

    const int gcol = j0 - 2 + lane;            // hist column this lane owns
    const bool colok = (unsigned)gcol < 1024u;
    const int gj = j0 + lane;                  // output column this lane stores
    const bool canstore = (lane < TWC) && (gj <= 1024);

    // 8 uniform per-channel plane base pointers
    float* po[8];
    #pragma unroll
    for (int o = 0; o < 8; ++o) po[o] = out + (size_t)(bb * 8 + o) * PLANE;

    const float* px = sx + (WTH * wv) * XC + lane;  // x row cursor (3 cols/lane)
    int hrow = rbase - 2;                      // global hist row of current step
    int orow = rbase;                          // global out row of next FIN
    int vo   = rbase * 1025 + gj;              // element offset within a plane

    // register state: d/w row-sum rings (slot = xrow & 3), contrib ping-pong,
    // pair-sum ring (slot = histrow & 3)
    float dd0, dd1, dd2, dd3, ww0, ww1, ww2, ww3;
    float cA[8], cB[8], PP0[8], PP1[8], PP2[8], PP3[8];

#define XROWLOAD(DD, WW) { \
    float n0 = px[0], n1 = px[1], n2 = px[2]; px += XC; \
    DD = n2 - n0; \
    WW = n0 + 2.0f*n1 + n2; \
}

// One hist row: load x row j+2 -> (DB,WB); Sobel from rings; magnitude;
// tournament argmax (== sequential first-max); one-hot contrib CC;
// pair sum PC = CP + CC; optional FIN of out row j-3.
#define HSTEP(DT, DM, DB, WT, WB, CP, CC, PR, PC, DOP, DOFIN) { \
    XROWLOAD(DB, WB) \
    float gx = DT + 2.0f*DM + DB; \
    float gy = WB - WT; \
    float msq = gx*gx + gy*gy; \
    float m = (colok && (unsigned)hrow < 1024u) \
                ? __builtin_amdgcn_sqrtf(msq) : 0.0f; \
    hrow++; \
    float pj0 = gx*wcn[0] + gy*wsn[0]; \
    float pj1 = gx*wcn[1] + gy*wsn[1]; \
    float pj2 = gx*wcn[2] + gy*wsn[2]; \
    float pj3 = gx*wcn[3] + gy*wsn[3]; \
    float pj4 = gx*wcn[4] + gy*wsn[4]; \
    float pj5 = gx*wcn[5] + gy*wsn[5]; \
    float pj6 = gx*wcn[6] + gy*wsn[6]; \
    float pj7 = gx*wcn[7] + gy*wsn[7]; \
    bool g01 = pj1 > pj0; float b01 = g01 ? pj1 : pj0; int i01 = g01 ? 1 : 0; \
    bool g23 = pj3 > pj2; float b23 = g23 ? pj3 : pj2; int i23 = g23 ? 3 : 2; \
    bool g45 = pj5 > pj4; float b45 = g45 ? pj5 : pj4; int i45 = g45 ? 5 : 4; \
    bool g67 = pj7 > pj6; float b67 = g67 ? pj7 : pj6; int i67 = g67 ? 7 : 6; \
    bool gA = b23 > b01; float bA = gA ? b23 : b01; int iA = gA ? i23 : i01; \
    bool gB = b67 > b45; float bB = gB ? b67 : b45; int iB = gB ? i67 : i45; \
    int idx = (bB > bA) ? iB : iA; \
    _Pragma("unroll") \
    for (int o = 0; o < 8; ++o) CC[o] = (idx == o) ? m : 0.0f; \
    if (DOP) { \
        _Pragma("unroll") \
        for (int o = 0; o < 8; ++o) PC[o] = CP[o] + CC[o]; \
    } \
    if (DOFIN) { \
        bool ok = canstore && (orow <= 1024); \
        _Pragma("unroll") \
        for (int o = 0; o < 8; ++o) { \
            float v = PR[o] + PC[o]; \
            v += wshl1(v);                 /* + lane l+1            */ \
            v += wshl1(wshl1(v));          /* + lanes l+2, l+3      */ \
            if (ok) __builtin_nontemporal_store(v, &po[o][vo]); \
        } \
        vo += 1025; orow++; \
    } \
}

    // prologue: x rows 0,1 then hist rows j=0..2 (no FIN yet)
    XROWLOAD(dd0, ww0)
    XROWLOAD(dd1, ww1)
    HSTEP(dd0, dd1, dd2, ww0, ww2, cA, cB, PP0, PP0, 0, 0)   // j=0 (P_0 unused)
    HSTEP(dd1, dd2, dd3, ww1, ww3, cB, cA, PP0, PP1, 1, 0)   // j=1
    HSTEP(dd2, dd3, dd0, ww2, ww0, cA, cB, PP0, PP2, 1, 0)   // j=2

    // steady state: j = 3..18, FIN t = j-3 = 0..15
    #pragma unroll 1
    for (int it = 0; it < 4; ++it) {
        HSTEP(dd3, dd0, dd1, ww3, ww1, cB, cA, PP1, PP3, 1, 1)   // j%4==3
        HSTEP(dd0, dd1, dd2, ww0, ww2, cA, cB, PP2, PP0, 1, 1)   // j%4==0
        HSTEP(dd1, dd2, dd3, ww1, ww3, cB, cA, PP3, PP1, 1, 1)   // j%4==1
        HSTEP(dd2, dd3, dd0, ww2, ww0, cA, cB, PP0, PP2, 1, 1)   // j%4==2
    }

#undef HSTEP
#undef XROWLOAD
}

extern "C" void kernel_launch(void* const* d_in, const int* in_sizes, int n_in,
                              void* d_out, int out_size, void* d_ws, size_t ws_size,
                              hipStream_t stream)
{
    (void)in_sizes; (void)n_in; (void)d_ws; (void)ws_size; (void)out_size;
    const float* x  = (const float*)d_in[0];
    const float* ow = (const float*)d_in[2];   // orient_w (10,2): rows 0..7 = [cos, sin]
    float* out = (float*)d_out;

    dim3 grid(NCT, NRT, 8);
    sift_fused<<<grid, 256, 0, stream>>>(x, ow, out);
}

// Round 13
// 91.266 us; speedup vs baseline: 1.6729x; 1.6729x over previous
//
#include <hip/hip_runtime.h>
#include <math.h>

// Fused SIFT-like pipeline:
//   Sobel(3x3, pad1) -> project onto 8 orientations -> argmax -> magnitude
//   into winning bin -> depthwise 4x4 ones conv (pad2) => out (8,8,1025,1025)
//
// v13 = v6 VERBATIM (proven 88.5us) with ONE structural change: WPB 4 -> 2
// (128-thread blocks, 61x32 tile, LDS 9.77KB) -> grid 4488 blocks =
// 17.5 blocks/CU available vs v6's 4.78. v6 was GRID-limited to ~19
// waves/CU; smaller blocks allow up to 32 waves/CU for latency hiding.
// launch_bounds(128,6): VGPR cap 85 (state ~60; v3 ran fine at cap 102).
// nt-store (the v10/v11 VGPR-28 catastrophe) permanently excluded.
//
// Block = 128 threads (2 waves), tile 61 out cols x 32 out rows; wave owns
// 16 rows. Lane l owns hist col j0-2+l; out col c = hist cols c..c+3 via
// v += shl1(v); v += shl1(shl1(v))  (wave_shl:1 DPP, zero-fill at lane 63;
// lanes 61..63 feed only and never store).

#define TWC 61              // out cols per tile
#define WTH 16              // out rows per wave
#define WPB 2               // waves per block
#define BTH (WPB*WTH)       // 32 out rows per block
#define XC 66               // staged x cols (j0-3 .. j0+62)
#define XR (BTH+5)          // 37 staged x rows
#define PLANE 1050625       // 1025*1025
#define NCT 17              // col tiles
#define NRT 33              // row tiles (33*32 = 1056 >= 1025)

// DPP wave_shl:1 (0x130): lane i <- lane i+1, zero-fill (== shfl_down 1;
// direction empirically proven by v6/v7/v8 passing)
__device__ __forceinline__ float wshl1(float v) {
    return __int_as_float(
        __builtin_amdgcn_update_dpp(0, __float_as_int(v), 0x130, 0xf, 0xf, true));
}

__global__ __launch_bounds__(128, 6)
void sift_fused(const float* __restrict__ x,
                const float* __restrict__ ow,
                float* __restrict__ out)
{
    __shared__ float sx[XR * XC];          // 9,768 B

    const int tid  = threadIdx.x;
    const int lane = tid & 63;
    const int wv   = tid >> 6;

    // XCD-aware remap: batch == XCD (4488 blocks, 4488%8==0, bijective)
    const int flat = blockIdx.x + NCT * (blockIdx.y + NRT * blockIdx.z);
    const int bb = flat & 7;
    const int t  = flat >> 3;              // 0..560 = 17*33-1
    const int bx = t % NCT;
    const int by = t / NCT;
    const int j0 = bx * TWC;
    const int r0 = by * BTH;

    // ---- stage x tile into LDS (zero-padded at image borders) ----
    const float* xb = x + (size_t)bb * 1024 * 1024;
    for (int p = tid; p < XR * XC; p += 128) {
        int r = p / XC, c = p - r * XC;
        int gr = r0 - 3 + r, gc = j0 - 3 + c;
        float v = 0.0f;
        if ((unsigned)gr < 1024u && (unsigned)gc < 1024u)
            v = xb[(size_t)gr * 1024 + gc];
        sx[p] = v;
    }
    __syncthreads();

    const int rbase = r0 + WTH * wv;           // first output row of this wave
    if (rbase > 1024) return;                  // no barriers after this point

    // orientation weights (uniform loads)
    float wcn[8], wsn[8];
    #pragma unroll
    for (int o = 0; o < 8; ++o) { wcn[o] = ow[2*o]; wsn[o] = ow[2*o+1]; }

    const int gcol = j0 - 2 + lane;            // hist column this lane owns
    const bool colok = (unsigned)gcol < 1024u;
    const int gj = j0 + lane;                  // output column this lane stores
    const bool canstore = (lane < TWC) && (gj <= 1024);

    // 8 uniform per-channel plane base pointers
    float* po[8];
    #pragma unroll
    for (int o = 0; o < 8; ++o) po[o] = out + (size_t)(bb * 8 + o) * PLANE;

    const float* px = sx + (WTH * wv) * XC + lane;  // x row cursor (3 cols/lane)
    int hrow = rbase - 2;                      // global hist row of current step
    int orow = rbase;                          // global out row of next FIN
    int vo   = rbase * 1025 + gj;              // element offset within a plane

    // register state: d/w row-sum rings (slot = xrow & 3), contrib ping-pong,
    // pair-sum ring (slot = histrow & 3)
    float dd0, dd1, dd2, dd3, ww0, ww1, ww2, ww3;
    float cA[8], cB[8], PP0[8], PP1[8], PP2[8], PP3[8];

#define XROWLOAD(DD, WW) { \
    float n0 = px[0], n1 = px[1], n2 = px[2]; px += XC; \
    DD = n2 - n0; \
    WW = n0 + 2.0f*n1 + n2; \
}

// One hist row: load x row j+2 -> (DB,WB); Sobel from rings; magnitude;
// tournament argmax (== sequential first-max); one-hot contrib CC;
// pair sum PC = CP + CC; optional FIN of out row j-3.
#define HSTEP(DT, DM, DB, WT, WB, CP, CC, PR, PC, DOP, DOFIN) { \
    XROWLOAD(DB, WB) \
    float gx = DT + 2.0f*DM + DB; \
    float gy = WB - WT; \
    float msq = gx*gx + gy*gy; \
    float m = (colok && (unsigned)hrow < 1024u) \
                ? __builtin_amdgcn_sqrtf(msq) : 0.0f; \
    hrow++; \
    float pj0 = gx*wcn[0] + gy*wsn[0]; \
    float pj1 = gx*wcn[1] + gy*wsn[1]; \
    float pj2 = gx*wcn[2] + gy*wsn[2]; \
    float pj3 = gx*wcn[3] + gy*wsn[3]; \
    float pj4 = gx*wcn[4] + gy*wsn[4]; \
    float pj5 = gx*wcn[5] + gy*wsn[5]; \
    float pj6 = gx*wcn[6] + gy*wsn[6]; \
    float pj7 = gx*wcn[7] + gy*wsn[7]; \
    bool g01 = pj1 > pj0; float b01 = g01 ? pj1 : pj0; int i01 = g01 ? 1 : 0; \
    bool g23 = pj3 > pj2; float b23 = g23 ? pj3 : pj2; int i23 = g23 ? 3 : 2; \
    bool g45 = pj5 > pj4; float b45 = g45 ? pj5 : pj4; int i45 = g45 ? 5 : 4; \
    bool g67 = pj7 > pj6; float b67 = g67 ? pj7 : pj6; int i67 = g67 ? 7 : 6; \
    bool gA = b23 > b01; float bA = gA ? b23 : b01; int iA = gA ? i23 : i01; \
    bool gB = b67 > b45; float bB = gB ? b67 : b45; int iB = gB ? i67 : i45; \
    int idx = (bB > bA) ? iB : iA; \
    _Pragma("unroll") \
    for (int o = 0; o < 8; ++o) CC[o] = (idx == o) ? m : 0.0f; \
    if (DOP) { \
        _Pragma("unroll") \
        for (int o = 0; o < 8; ++o) PC[o] = CP[o] + CC[o]; \
    } \
    if (DOFIN) { \
        bool ok = canstore && (orow <= 1024); \
        _Pragma("unroll") \
        for (int o = 0; o < 8; ++o) { \
            float v = PR[o] + PC[o]; \
            v += wshl1(v);                 /* + lane l+1            */ \
            v += wshl1(wshl1(v));          /* + lanes l+2, l+3      */ \
            if (ok) po[o][vo] = v; \
        } \
        vo += 1025; orow++; \
    } \
}

    // prologue: x rows 0,1 then hist rows j=0..2 (no FIN yet)
    XROWLOAD(dd0, ww0)
    XROWLOAD(dd1, ww1)
    HSTEP(dd0, dd1, dd2, ww0, ww2, cA, cB, PP0, PP0, 0, 0)   // j=0 (P_0 unused)
    HSTEP(dd1, dd2, dd3, ww1, ww3, cB, cA, PP0, PP1, 1, 0)   // j=1
    HSTEP(dd2, dd3, dd0, ww2, ww0, cA, cB, PP0, PP2, 1, 0)   // j=2

    // steady state: j = 3..18, FIN t = j-3 = 0..15
    #pragma unroll 1
    for (int it = 0; it < 4; ++it) {
        HSTEP(dd3, dd0, dd1, ww3, ww1, cB, cA, PP1, PP3, 1, 1)   // j%4==3
        HSTEP(dd0, dd1, dd2, ww0, ww2, cA, cB, PP2, PP0, 1, 1)   // j%4==0
        HSTEP(dd1, dd2, dd3, ww1, ww3, cB, cA, PP3, PP1, 1, 1)   // j%4==1
        HSTEP(dd2, dd3, dd0, ww2, ww0, cA, cB, PP0, PP2, 1, 1)   // j%4==2
    }

#undef HSTEP
#undef XROWLOAD
}

extern "C" void kernel_launch(void* const* d_in, const int* in_sizes, int n_in,
                              void* d_out, int out_size, void* d_ws, size_t ws_size,
                              hipStream_t stream)
{
    (void)in_sizes; (void)n_in; (void)d_ws; (void)ws_size; (void)out_size;
    const float* x  = (const float*)d_in[0];
    const float* ow = (const float*)d_in[2];   // orient_w (10,2): rows 0..7 = [cos, sin]
    float* out = (float*)d_out;

    dim3 grid(NCT, NRT, 8);                    // 4488 blocks
    sift_fused<<<grid, 128, 0, stream>>>(x, ow, out);
}

// Round 14
// 84.382 us; speedup vs baseline: 1.8093x; 1.0816x over previous
//
#include <hip/hip_runtime.h>
#include <math.h>

// Fused SIFT-like pipeline:
//   Sobel(3x3, pad1) -> project onto 8 orientations -> argmax -> magnitude
//   into winning bin -> depthwise 4x4 ones conv (pad2) => out (8,8,1025,1025)
//
// v14 = v6 (proven 88.5us) with ONE change: octant fast-path argmax.
// The 8 orientations are evenly spaced (22.5 + 45k deg), so argmax of the
// projections == angular octant of (gx,gy): 3 compares + selects (~10 ops)
// instead of 16 proj + 21 tournament ops. Near the octant bisectors
// (gx=0 / gy=0 / |gx|=|gy|, rel zone 2^-14) the whole wave falls back to
// the bit-exact projection+tournament path (exact tie semantics preserved;
// fallback rate ~1% of wave-steps).
//
// Block = 256 threads (4 waves), tile 61 out cols x 64 out rows; wave owns
// 16 rows. Lane l owns hist col j0-2+l; out col c = hist cols c..c+3 via
// DPP wave_shl:1 chains. batch==XCD swizzle. launch_bounds(256,4).

#define TWC 61              // out cols per tile
#define WTH 16              // out rows per wave
#define WPB 4               // waves per block
#define BTH (WPB*WTH)       // 64 out rows per block
#define XC 66               // staged x cols (j0-3 .. j0+62)
#define XR (BTH+5)          // 69 staged x rows
#define PLANE 1050625       // 1025*1025
#define NCT 17              // col tiles
#define NRT 17              // row tiles

// DPP wave_shl:1 (0x130): lane i <- lane i+1, zero-fill (== shfl_down 1)
__device__ __forceinline__ float wshl1(float v) {
    return __int_as_float(
        __builtin_amdgcn_update_dpp(0, __float_as_int(v), 0x130, 0xf, 0xf, true));
}

__global__ __launch_bounds__(256, 4)
void sift_fused(const float* __restrict__ x,
                const float* __restrict__ ow,
                float* __restrict__ out)
{
    __shared__ float sx[XR * XC];

    const int tid  = threadIdx.x;
    const int lane = tid & 63;
    const int wv   = tid >> 6;

    // XCD-aware remap: batch == XCD (8 batches, 8 XCDs, bijective)
    const int flat = blockIdx.x + NCT * (blockIdx.y + NRT * blockIdx.z);
    const int bb = flat & 7;
    const int t  = flat >> 3;
    const int bx = t % NCT;
    const int by = t / NCT;
    const int j0 = bx * TWC;
    const int r0 = by * BTH;

    // ---- stage x tile into LDS (zero-padded at image borders) ----
    const float* xb = x + (size_t)bb * 1024 * 1024;
    for (int p = tid; p < XR * XC; p += 256) {
        int r = p / XC, c = p - r * XC;
        int gr = r0 - 3 + r, gc = j0 - 3 + c;
        float v = 0.0f;
        if ((unsigned)gr < 1024u && (unsigned)gc < 1024u)
            v = xb[(size_t)gr * 1024 + gc];
        sx[p] = v;
    }
    __syncthreads();

    const int rbase = r0 + WTH * wv;           // first output row of this wave
    if (rbase > 1024) return;                  // no barriers after this point

    // orientation weights (uniform loads; used by exact fallback path)
    float wcn[8], wsn[8];
    #pragma unroll
    for (int o = 0; o < 8; ++o) { wcn[o] = ow[2*o]; wsn[o] = ow[2*o+1]; }

    const int gcol = j0 - 2 + lane;            // hist column this lane owns
    const bool colok = (unsigned)gcol < 1024u;
    const int gj = j0 + lane;                  // output column this lane stores
    const bool canstore = (lane < TWC) && (gj <= 1024);

    // 8 uniform per-channel plane base pointers
    float* po[8];
    #pragma unroll
    for (int o = 0; o < 8; ++o) po[o] = out + (size_t)(bb * 8 + o) * PLANE;

    const float* px = sx + (WTH * wv) * XC + lane;  // x row cursor (3 cols/lane)
    int hrow = rbase - 2;                      // global hist row of current step
    int orow = rbase;                          // global out row of next FIN
    int vo   = rbase * 1025 + gj;              // element offset within a plane

    // register state: d/w row-sum rings (slot = xrow & 3), contrib ping-pong,
    // pair-sum ring (slot = histrow & 3)
    float dd0, dd1, dd2, dd3, ww0, ww1, ww2, ww3;
    float cA[8], cB[8], PP0[8], PP1[8], PP2[8], PP3[8];

#define XROWLOAD(DD, WW) { \
    float n0 = px[0], n1 = px[1], n2 = px[2]; px += XC; \
    DD = n2 - n0; \
    WW = n0 + 2.0f*n1 + n2; \
}

// One hist row: load x row j+2 -> (DB,WB); Sobel from rings; magnitude;
// argmax: octant fast path, wave-uniform fallback to bit-exact
// projection+tournament near bisectors; one-hot contrib CC;
// pair sum PC = CP + CC; optional FIN of out row j-3.
#define HSTEP(DT, DM, DB, WT, WB, CP, CC, PR, PC, DOP, DOFIN) { \
    XROWLOAD(DB, WB) \
    float gx = DT + 2.0f*DM + DB; \
    float gy = WB - WT; \
    float msq = gx*gx + gy*gy; \
    float m = (colok && (unsigned)hrow < 1024u) \
                ? __builtin_amdgcn_sqrtf(msq) : 0.0f; \
    hrow++; \
    float ax_ = fabsf(gx), ay_ = fabsf(gy); \
    bool risky_ = fminf(fminf(ax_, ay_), fabsf(ay_ - ax_)) \
                    < 6.103515625e-5f * (ax_ + ay_); \
    int idx; \
    if (__any(risky_)) { \
        float pj0 = gx*wcn[0] + gy*wsn[0]; \
        float pj1 = gx*wcn[1] + gy*wsn[1]; \
        float pj2 = gx*wcn[2] + gy*wsn[2]; \
        float pj3 = gx*wcn[3] + gy*wsn[3]; \
        float pj4 = gx*wcn[4] + gy*wsn[4]; \
        float pj5 = gx*wcn[5] + gy*wsn[5]; \
        float pj6 = gx*wcn[6] + gy*wsn[6]; \
        float pj7 = gx*wcn[7] + gy*wsn[7]; \
        bool g01 = pj1 > pj0; float b01 = g01 ? pj1 : pj0; int i01 = g01 ? 1 : 0; \
        bool g23 = pj3 > pj2; float b23 = g23 ? pj3 : pj2; int i23 = g23 ? 3 : 2; \
        bool g45 = pj5 > pj4; float b45 = g45 ? pj5 : pj4; int i45 = g45 ? 5 : 4; \
        bool g67 = pj7 > pj6; float b67 = g67 ? pj7 : pj6; int i67 = g67 ? 7 : 6; \
        bool gA = b23 > b01; float bA = gA ? b23 : b01; int iA = gA ? i23 : i01; \
        bool gB = b67 > b45; float bB = gB ? b67 : b45; int iB = gB ? i67 : i45; \
        idx = (bB > bA) ? iB : iA; \
    } else { \
        bool a_ = gy < 0.0f, b_ = gx < 0.0f; \
        int c_ = (ay_ >= ax_) ? 1 : 0; \
        idx = b_ ? (a_ ? (4 + c_) : (3 - c_)) \
                 : (a_ ? (7 - c_) : c_); \
    } \
    _Pragma("unroll") \
    for (int o = 0; o < 8; ++o) CC[o] = (idx == o) ? m : 0.0f; \
    if (DOP) { \
        _Pragma("unroll") \
        for (int o = 0; o < 8; ++o) PC[o] = CP[o] + CC[o]; \
    } \
    if (DOFIN) { \
        bool ok = canstore && (orow <= 1024); \
        _Pragma("unroll") \
        for (int o = 0; o < 8; ++o) { \
            float v = PR[o] + PC[o]; \
            v += wshl1(v);                 /* + lane l+1            */ \
            v += wshl1(wshl1(v));          /* + lanes l+2, l+3      */ \
            if (ok) po[o][vo] = v; \
        } \
        vo += 1025; orow++; \
    } \
}

    // prologue: x rows 0,1 then hist rows j=0..2 (no FIN yet)
    XROWLOAD(dd0, ww0)
    XROWLOAD(dd1, ww1)
    HSTEP(dd0, dd1, dd2, ww0, ww2, cA, cB, PP0, PP0, 0, 0)   // j=0 (P_0 unused)
    HSTEP(dd1, dd2, dd3, ww1, ww3, cB, cA, PP0, PP1, 1, 0)   // j=1
    HSTEP(dd2, dd3, dd0, ww2, ww0, cA, cB, PP0, PP2, 1, 0)   // j=2

    // steady state: j = 3..18, FIN t = j-3 = 0..15
    #pragma unroll 1
    for (int it = 0; it < 4; ++it) {
        HSTEP(dd3, dd0, dd1, ww3, ww1, cB, cA, PP1, PP3, 1, 1)   // j%4==3
        HSTEP(dd0, dd1, dd2, ww0, ww2, cA, cB, PP2, PP0, 1, 1)   // j%4==0
        HSTEP(dd1, dd2, dd3, ww1, ww3, cB, cA, PP3, PP1, 1, 1)   // j%4==1
        HSTEP(dd2, dd3, dd0, ww2, ww0, cA, cB, PP0, PP2, 1, 1)   // j%4==2
    }

#undef HSTEP
#undef XROWLOAD
}

extern "C" void kernel_launch(void* const* d_in, const int* in_sizes, int n_in,
                              void* d_out, int out_size, void* d_ws, size_t ws_size,
                              hipStream_t stream)
{
    (void)in_sizes; (void)n_in; (void)d_ws; (void)ws_size; (void)out_size;
    const float* x  = (const float*)d_in[0];
    const float* ow = (const float*)d_in[2];   // orient_w (10,2): rows 0..7 = [cos, sin]
    float* out = (float*)d_out;

    dim3 grid(NCT, NRT, 8);
    sift_fused<<<grid, 256, 0, stream>>>(x, ow, out);
}

// Round 15
// 84.019 us; speedup vs baseline: 1.8172x; 1.0043x over previous
//
#include <hip/hip_runtime.h>
#include <math.h>

// Fused SIFT-like pipeline:
//   Sobel(3x3, pad1) -> project onto 8 orientations -> argmax -> magnitude
//   into winning bin -> depthwise 4x4 ones conv (pad2) => out (8,8,1025,1025)
//
// v15 = v14 (84.4us: octant argmax + bisector fallback, batch==XCD swizzle,
// DPP horizontal sums) with ONE change: LDS stages pre-reduced (d,w) pairs
// (d = x[c+1]-x[c-1], w = x[c-1]+2x[c]+x[c+1], the exact v6 trees -> gx/gy
// bit-identical) instead of raw x. HSTEP: ONE aligned ds_read_b64 per step
// instead of 3 unaligned ds_read_b32 + 4 VALU. LDS 35.3KB -> same 4
// blocks/CU residency as v6.
//
// Block = 256 threads (4 waves), tile 61 out cols x 64 out rows; wave owns
// 16 rows. Lane l owns hist col j0-2+l; out col c = hist cols c..c+3 via
// DPP wave_shl:1 chains. launch_bounds(256,4).

#define TWC 61              // out cols per tile
#define WTH 16              // out rows per wave
#define WPB 4               // waves per block
#define BTH (WPB*WTH)       // 64 out rows per block
#define XR (BTH+5)          // 69 staged x rows
#define PLANE 1050625       // 1025*1025
#define NCT 17              // col tiles
#define NRT 17              // row tiles

// DPP wave_shl:1 (0x130): lane i <- lane i+1, zero-fill (== shfl_down 1)
__device__ __forceinline__ float wshl1(float v) {
    return __int_as_float(
        __builtin_amdgcn_update_dpp(0, __float_as_int(v), 0x130, 0xf, 0xf, true));
}

__global__ __launch_bounds__(256, 4)
void sift_fused(const float* __restrict__ x,
                const float* __restrict__ ow,
                float* __restrict__ out)
{
    // (d,w) float2 per (staged row, lane-col q): q in [0,64) <-> col j0-2+q
    __shared__ float sdw[XR * 128];        // 35,328 B

    const int tid  = threadIdx.x;
    const int lane = tid & 63;
    const int wv   = tid >> 6;

    // XCD-aware remap: batch == XCD (8 batches, 8 XCDs, bijective)
    const int flat = blockIdx.x + NCT * (blockIdx.y + NRT * blockIdx.z);
    const int bb = flat & 7;
    const int t  = flat >> 3;
    const int bx = t % NCT;
    const int by = t / NCT;
    const int j0 = bx * TWC;
    const int r0 = by * BTH;

    // ---- stage (d,w) rows: 16 groups of 4 cols per row ----
    const float* xb = x + (size_t)bb * 1024 * 1024;
    for (int s = tid; s < XR * 16; s += 256) {
        int r = s >> 4, g = s & 15;
        int grow = r0 - 3 + r;
        float4 o1, o2;
        if ((unsigned)grow < 1024u) {
            const float* rp = xb + ((size_t)(unsigned)grow << 10);
            int cb = j0 - 3 + 4 * g;       // x col of xv[0]
            float xv0, xv1, xv2, xv3, xv4, xv5;
            {
                int c;
                c = cb;     xv0 = ((unsigned)c < 1024u) ? rp[c] : 0.0f;
                c = cb + 1; xv1 = ((unsigned)c < 1024u) ? rp[c] : 0.0f;
                c = cb + 2; xv2 = ((unsigned)c < 1024u) ? rp[c] : 0.0f;
                c = cb + 3; xv3 = ((unsigned)c < 1024u) ? rp[c] : 0.0f;
                c = cb + 4; xv4 = ((unsigned)c < 1024u) ? rp[c] : 0.0f;
                c = cb + 5; xv5 = ((unsigned)c < 1024u) ? rp[c] : 0.0f;
            }
            // (d,w) for center cols cb+1..cb+4  (= hist cols j0-2+4g..+3)
            o1.x = xv2 - xv0;  o1.y = xv0 + 2.0f*xv1 + xv2;
            o1.z = xv3 - xv1;  o1.w = xv1 + 2.0f*xv2 + xv3;
            o2.x = xv4 - xv2;  o2.y = xv2 + 2.0f*xv3 + xv4;
            o2.z = xv5 - xv3;  o2.w = xv3 + 2.0f*xv4 + xv5;
        } else {
            o1.x=0.f;o1.y=0.f;o1.z=0.f;o1.w=0.f;
            o2.x=0.f;o2.y=0.f;o2.z=0.f;o2.w=0.f;
        }
        float* dst = &sdw[(r * 64 + 4 * g) * 2];
        *reinterpret_cast<float4*>(dst)     = o1;
        *reinterpret_cast<float4*>(dst + 4) = o2;
    }
    __syncthreads();

    const int rbase = r0 + WTH * wv;           // first output row of this wave
    if (rbase > 1024) return;                  // no barriers after this point

    // orientation weights (uniform loads; used by exact fallback path)
    float wcn[8], wsn[8];
    #pragma unroll
    for (int o = 0; o < 8; ++o) { wcn[o] = ow[2*o]; wsn[o] = ow[2*o+1]; }

    const int gcol = j0 - 2 + lane;            // hist column this lane owns
    const bool colok = (unsigned)gcol < 1024u;
    const int gj = j0 + lane;                  // output column this lane stores
    const bool canstore = (lane < TWC) && (gj <= 1024);

    // 8 uniform per-channel plane base pointers
    float* po[8];
    #pragma unroll
    for (int o = 0; o < 8; ++o) po[o] = out + (size_t)(bb * 8 + o) * PLANE;

    // (d,w) cursor: wave's first staged row, this lane's column
    const float2* pdw = reinterpret_cast<const float2*>(sdw)
                        + (WTH * wv) * 64 + lane;
    int hrow = rbase - 2;                      // global hist row of current step
    int orow = rbase;                          // global out row of next FIN
    int vo   = rbase * 1025 + gj;              // element offset within a plane

    // register state: d/w row rings (slot = xrow & 3), contrib ping-pong,
    // pair-sum ring (slot = histrow & 3)
    float dd0, dd1, dd2, dd3, ww0, ww1, ww2, ww3;
    float cA[8], cB[8], PP0[8], PP1[8], PP2[8], PP3[8];

#define XROWLOAD(DD, WW) { \
    float2 rdw_ = *pdw; pdw += 64; \
    DD = rdw_.x; WW = rdw_.y; \
}

// One hist row: load (d,w) row j+2 -> (DB,WB); Sobel from rings; magnitude;
// argmax: octant fast path, wave-uniform fallback to bit-exact
// projection+tournament near bisectors; one-hot contrib CC;
// pair sum PC = CP + CC; optional FIN of out row j-3.
#define HSTEP(DT, DM, DB, WT, WB, CP, CC, PR, PC, DOP, DOFIN) { \
    XROWLOAD(DB, WB) \
    float gx = DT + 2.0f*DM + DB; \
    float gy = WB - WT; \
    float msq = gx*gx + gy*gy; \
    float m = (colok && (unsigned)hrow < 1024u) \
                ? __builtin_amdgcn_sqrtf(msq) : 0.0f; \
    hrow++; \
    float ax_ = fabsf(gx), ay_ = fabsf(gy); \
    bool risky_ = fminf(fminf(ax_, ay_), fabsf(ay_ - ax_)) \
                    < 6.103515625e-5f * (ax_ + ay_); \
    int idx; \
    if (__any(risky_)) { \
        float pj0 = gx*wcn[0] + gy*wsn[0]; \
        float pj1 = gx*wcn[1] + gy*wsn[1]; \
        float pj2 = gx*wcn[2] + gy*wsn[2]; \
        float pj3 = gx*wcn[3] + gy*wsn[3]; \
        float pj4 = gx*wcn[4] + gy*wsn[4]; \
        float pj5 = gx*wcn[5] + gy*wsn[5]; \
        float pj6 = gx*wcn[6] + gy*wsn[6]; \
        float pj7 = gx*wcn[7] + gy*wsn[7]; \
        bool g01 = pj1 > pj0; float b01 = g01 ? pj1 : pj0; int i01 = g01 ? 1 : 0; \
        bool g23 = pj3 > pj2; float b23 = g23 ? pj3 : pj2; int i23 = g23 ? 3 : 2; \
        bool g45 = pj5 > pj4; float b45 = g45 ? pj5 : pj4; int i45 = g45 ? 5 : 4; \
        bool g67 = pj7 > pj6; float b67 = g67 ? pj7 : pj6; int i67 = g67 ? 7 : 6; \
        bool gA = b23 > b01; float bA = gA ? b23 : b01; int iA = gA ? i23 : i01; \
        bool gB = b67 > b45; float bB = gB ? b67 : b45; int iB = gB ? i67 : i45; \
        idx = (bB > bA) ? iB : iA; \
    } else { \
        bool a_ = gy < 0.0f, b_ = gx < 0.0f; \
        int c_ = (ay_ >= ax_) ? 1 : 0; \
        idx = b_ ? (a_ ? (4 + c_) : (3 - c_)) \
                 : (a_ ? (7 - c_) : c_); \
    } \
    _Pragma("unroll") \
    for (int o = 0; o < 8; ++o) CC[o] = (idx == o) ? m : 0.0f; \
    if (DOP) { \
        _Pragma("unroll") \
        for (int o = 0; o < 8; ++o) PC[o] = CP[o] + CC[o]; \
    } \
    if (DOFIN) { \
        bool ok = canstore && (orow <= 1024); \
        _Pragma("unroll") \
        for (int o = 0; o < 8; ++o) { \
            float v = PR[o] + PC[o]; \
            v += wshl1(v);                 /* + lane l+1            */ \
            v += wshl1(wshl1(v));          /* + lanes l+2, l+3      */ \
            if (ok) po[o][vo] = v; \
        } \
        vo += 1025; orow++; \
    } \
}

    // prologue: (d,w) rows 0,1 then hist rows j=0..2 (no FIN yet)
    XROWLOAD(dd0, ww0)
    XROWLOAD(dd1, ww1)
    HSTEP(dd0, dd1, dd2, ww0, ww2, cA, cB, PP0, PP0, 0, 0)   // j=0 (P_0 unused)
    HSTEP(dd1, dd2, dd3, ww1, ww3, cB, cA, PP0, PP1, 1, 0)   // j=1
    HSTEP(dd2, dd3, dd0, ww2, ww0, cA, cB, PP0, PP2, 1, 0)   // j=2

    // steady state: j = 3..18, FIN t = j-3 = 0..15
    #pragma unroll 1
    for (int it = 0; it < 4; ++it) {
        HSTEP(dd3, dd0, dd1, ww3, ww1, cB, cA, PP1, PP3, 1, 1)   // j%4==3
        HSTEP(dd0, dd1, dd2, ww0, ww2, cA, cB, PP2, PP0, 1, 1)   // j%4==0
        HSTEP(dd1, dd2, dd3, ww1, ww3, cB, cA, PP3, PP1, 1, 1)   // j%4==1
        HSTEP(dd2, dd3, dd0, ww2, ww0, cA, cB, PP0, PP2, 1, 1)   // j%4==2
    }

#undef HSTEP
#undef XROWLOAD
}

extern "C" void kernel_launch(void* const* d_in, const int* in_sizes, int n_in,
                              void* d_out, int out_size, void* d_ws, size_t ws_size,
                              hipStream_t stream)
{
    (void)in_sizes; (void)n_in; (void)d_ws; (void)ws_size; (void)out_size;
    const float* x  = (const float*)d_in[0];
    const float* ow = (const float*)d_in[2];   // orient_w (10,2): rows 0..7 = [cos, sin]
    float* out = (float*)d_out;

    dim3 grid(NCT, NRT, 8);
    sift_fused<<<grid, 256, 0, stream>>>(x, ow, out);
}